// Round 10
// baseline (429.287 us; speedup 1.0000x reference)
//
#include <hip/hip_runtime.h>
#include <hip/hip_bf16.h>

// Problem dims (fixed by setup_inputs): B=4, S=2048, DIN=4096, DOUT=4096, GS=32
#define DIN   4096
#define DOUT  4096
#define MROWS 8192            // B*S
#define GSIZE 32
#define NGPR  (DIN / GSIZE)   // groups per row = 128
#define NG_ACT (MROWS * NGPR) // 1048576
#define NG_W   (DOUT * NGPR)  // 524288

typedef __bf16 bf16_t;
typedef __attribute__((ext_vector_type(8))) __bf16 bf16x8;
typedef __attribute__((ext_vector_type(4))) float f32x4;

typedef const __attribute__((address_space(1))) void* gptr_t;
typedef __attribute__((address_space(3))) void* lptr_t;

// floor(log2(max(a,1))) grid rounding to the FP4 E2M1 set {0,±0.5,1,1.5,2,3,4,6}
__device__ __forceinline__ float fp4_round(float y) {
  float a  = __builtin_fabsf(y);
  float am = fmaxf(a, 1.0f);
  int   e  = (int)((__float_as_uint(am) >> 23) & 255u) - 127;  // floor(log2(max(a,1)))
  float step = __uint_as_float((unsigned)(e - 1 + 127) << 23); // 2^(e-1): 0.5, 1, 2
  float q = rintf(a / step) * step;  // RNE, matches jnp.round
  q = fminf(q, 6.0f);
  return copysignf(q, y);
}

// ---------------- activation quant: one thread per group of 32 ----------------
__global__ __launch_bounds__(256) void act_quant(const float* __restrict__ x,
                                                 bf16_t* __restrict__ xq,
                                                 float* __restrict__ exps_out) {
  int g = blockIdx.x * 256 + threadIdx.x;
  const float4* xp = reinterpret_cast<const float4*>(x) + (size_t)g * 8;
  float v[32];
  float amax = 0.f;
#pragma unroll
  for (int i = 0; i < 8; ++i) {
    float4 t = xp[i];
    v[4*i+0] = t.x; v[4*i+1] = t.y; v[4*i+2] = t.z; v[4*i+3] = t.w;
    amax = fmaxf(amax, fmaxf(fmaxf(__builtin_fabsf(t.x), __builtin_fabsf(t.y)),
                             fmaxf(__builtin_fabsf(t.z), __builtin_fabsf(t.w))));
  }
  float exps = 0.f;
  if (amax > 0.f) {
    float am = fmaxf(amax, 1e-30f);
    exps = (float)((int)((__float_as_uint(am) >> 23) & 255u) - 129);  // floor(log2)-2
  }
  float scale = __uint_as_float((unsigned)((int)exps + 127) << 23);   // 2^exps (exact)
  float inv   = __uint_as_float((unsigned)(127 - (int)exps) << 23);   // 2^-exps (exact)
  bf16x8 hv[4];
#pragma unroll
  for (int i = 0; i < 32; ++i) {
    float q = fp4_round(v[i] * inv) * scale;  // exact: pow2 scaling both ways
    hv[i >> 3][i & 7] = (bf16_t)q;            // exact in bf16 (<=2 mantissa bits * 2^e)
  }
  bf16x8* dst = reinterpret_cast<bf16x8*>(xq + (size_t)g * 32);
#pragma unroll
  for (int i = 0; i < 4; ++i) dst[i] = hv[i];
  exps_out[g] = exps;
}

// ---------------- weight quant with (1+eps_eff) scale ----------------
__global__ __launch_bounds__(256) void w_quant(const float* __restrict__ w,
                                               const float* __restrict__ eps,
                                               const float* __restrict__ adv,
                                               bf16_t* __restrict__ wq,
                                               float* __restrict__ eps_eff_out,
                                               float* __restrict__ w_exps_out) {
  int g = blockIdx.x * 256 + threadIdx.x;
  float ee = eps[g] + adv[g];
  eps_eff_out[g] = ee;
  const float4* wp = reinterpret_cast<const float4*>(w) + (size_t)g * 8;
  float v[32];
  float amax = 0.f;
#pragma unroll
  for (int i = 0; i < 8; ++i) {
    float4 t = wp[i];
    v[4*i+0] = t.x; v[4*i+1] = t.y; v[4*i+2] = t.z; v[4*i+3] = t.w;
    amax = fmaxf(amax, fmaxf(fmaxf(__builtin_fabsf(t.x), __builtin_fabsf(t.y)),
                             fmaxf(__builtin_fabsf(t.z), __builtin_fabsf(t.w))));
  }
  float exps = 0.f;
  if (amax > 0.f) {
    float am = fmaxf(amax, 1e-30f);
    exps = (float)((int)((__float_as_uint(am) >> 23) & 255u) - 129);
  }
  w_exps_out[g] = exps;
  float p2   = __uint_as_float((unsigned)((int)exps + 127) << 23);  // 2^exps
  float scale = p2 * (1.0f + ee);                                   // matches reference order
  bf16x8 hv[4];
#pragma unroll
  for (int i = 0; i < 32; ++i) {
    float q = fp4_round(v[i] / scale) * scale;  // IEEE div, matches reference
    hv[i >> 3][i & 7] = (bf16_t)q;              // only bf16-rounding error source
  }
  bf16x8* dst = reinterpret_cast<bf16x8*>(wq + (size_t)g * 32);
#pragma unroll
  for (int i = 0; i < 4; ++i) dst[i] = hv[i];
}

// ---------------- bf16 GEMM: C[M,N] = A[M,K] * B[N,K]^T + bias ----------------
// r10 = r9 (cross-block TLP: 128x128 tile, BK=32, 4 waves, triple-buffered
// 48 KiB LDS, 3 blocks/CU) with two fixes:
// (1) CORRECT bank swizzle for 64-B rows: f(row) = (row>>1)&3 (r9's (row>>2)&3
//     left 2-way collisions in every 8-lane group -> 3.36e7 conflicts, 2x LDS
//     read time). Now each 8-lane group covers all 32 banks: rows alternate
//     16-bank halves via row&1; within a parity class the 4 lanes hit 4
//     distinct slots. Staging source chunk = (l&3)^((l>>3)&3) (row = l>>2);
//     read slot = ((lane>>4)^((lane>>1)&3))<<4 (row bits 1-2 = lane bits 1-2).
//     XOR involution on both sides (rule #21).
// (2) Unroll K-loop by 3 with static buffer indices (kills per-iter %3 VALU
//     and dynamic LDS base).
// Per K-step (ONE barrier): STG(j+2) | 8 ds_read_b128 | 16 MFMA |
// sched_barrier | lgkm(0) | vmcnt(4) (tile j+1 landed, j+2 in flight; never 0
// in steady state) | s_barrier | sched_barrier. Overlap comes from 3
// independent blocks/CU (m114 mechanism), not intra-block scheduling.
__global__ __launch_bounds__(256, 3) void gemm_bt(const bf16_t* __restrict__ A,
                                                  const bf16_t* __restrict__ B,
                                                  const float* __restrict__ bias,
                                                  float* __restrict__ C) {
  __shared__ bf16_t sA[3 * 4096];   // 3 bufs x 128 rows x 32 cols
  __shared__ bf16_t sB[3 * 4096];
  const int tid  = threadIdx.x;
  const int wave = tid >> 6;   // 0..3
  const int lane = tid & 63;

  // T1: bijective XCD swizzle (2048 blocks, 2048 % 8 == 0)
  const int swz = (blockIdx.x & 7) * 256 + (blockIdx.x >> 3);
  const int tm0 = (swz >> 5) * 128;   // 64 M-tiles
  const int tn0 = (swz & 31) * 128;   // 32 N-tiles

  const int wr = wave >> 1;   // 0..1 : M-half (64 rows)
  const int wc = wave & 1;    // 0..1 : N-half (64 cols)

  // ---- staging: per wave 4 gload_lds (A rows [w*32,+32), B rows [w*32,+32)) ----
  const int lr = lane >> 2;                               // staged row 0..15
  const int lc = ((lane & 3) ^ ((lane >> 3) & 3)) * 8;    // pre-swizzled src chunk
  const bf16_t* gA = A + (size_t)(tm0 + wave * 32 + lr) * DIN + lc;
  const bf16_t* gB = B + (size_t)(tn0 + wave * 32 + lr) * DIN + lc;
  const int dst0 = wave * 1024;   // elems within one buf (32 rows x 32 cols)

#define STG(kt, bf) do {                                                            \
    const bf16_t* a_ = gA + (size_t)(kt) * 32;                                      \
    const bf16_t* b_ = gB + (size_t)(kt) * 32;                                      \
    __builtin_amdgcn_global_load_lds((gptr_t)a_,                                    \
        (lptr_t)(sA + (bf) * 4096 + dst0), 16, 0, 0);                               \
    __builtin_amdgcn_global_load_lds((gptr_t)(a_ + (size_t)16 * DIN),               \
        (lptr_t)(sA + (bf) * 4096 + dst0 + 512), 16, 0, 0);                         \
    __builtin_amdgcn_global_load_lds((gptr_t)b_,                                    \
        (lptr_t)(sB + (bf) * 4096 + dst0), 16, 0, 0);                               \
    __builtin_amdgcn_global_load_lds((gptr_t)(b_ + (size_t)16 * DIN),               \
        (lptr_t)(sB + (bf) * 4096 + dst0 + 512), 16, 0, 0);                         \
  } while (0)

  // ---- fragment read offsets: byte = row*64 + 16*((lane>>4) ^ ((row>>1)&3))
  // row = wseg + m*16 + (lane&15) -> (row>>1)&3 == (lane>>1)&3
  const int slot  = (((lane >> 4) ^ ((lane >> 1) & 3)) << 4);
  const int apart = (wr * 64 + (lane & 15)) * 64 + slot;
  const int bpart = (wc * 64 + (lane & 15)) * 64 + slot;

  f32x4 acc[4][4] = {};

  // ---- prologue: tiles 0,1 staged; tile 0 landed, tile 1 in flight ----
  STG(0, 0); STG(1, 1);
  asm volatile("s_waitcnt vmcnt(4)");
  __builtin_amdgcn_s_barrier();
  __builtin_amdgcn_sched_barrier(0);

#define KSTEP(J, RB, SB, DO_STAGE, VMW) do {                                        \
    if (DO_STAGE) STG((J) + 2, SB);                                                 \
    const char* bA_ = (const char*)sA + (RB) * 8192;                                \
    const char* bB_ = (const char*)sB + (RB) * 8192;                                \
    bf16x8 a_[4], b_[4];                                                            \
    _Pragma("unroll")                                                               \
    for (int m_ = 0; m_ < 4; ++m_)                                                  \
      a_[m_] = *reinterpret_cast<const bf16x8*>(bA_ + apart + m_ * 1024);           \
    _Pragma("unroll")                                                               \
    for (int n_ = 0; n_ < 4; ++n_)                                                  \
      b_[n_] = *reinterpret_cast<const bf16x8*>(bB_ + bpart + n_ * 1024);           \
    _Pragma("unroll")                                                               \
    for (int m_ = 0; m_ < 4; ++m_)                                                  \
      _Pragma("unroll")                                                             \
      for (int n_ = 0; n_ < 4; ++n_)                                                \
        acc[m_][n_] = __builtin_amdgcn_mfma_f32_16x16x32_bf16(a_[m_], b_[n_],       \
                                                              acc[m_][n_], 0, 0, 0);\
    __builtin_amdgcn_sched_barrier(0);                                              \
    asm volatile("s_waitcnt lgkmcnt(0)");                                           \
    asm volatile("s_waitcnt vmcnt(" #VMW ")");                                      \
    __builtin_amdgcn_s_barrier();                                                   \
    __builtin_amdgcn_sched_barrier(0);                                              \
  } while (0)

  for (int j = 0; j < 126; j += 3) {
    KSTEP(j,     0, 2, 1, 4);   // read buf0, stage j+2 -> buf2
    KSTEP(j + 1, 1, 0, 1, 4);   // read buf1, stage j+3 -> buf0
    KSTEP(j + 2, 2, 1, 1, 4);   // read buf2, stage j+4 -> buf1
  }
  KSTEP(126, 0, 0, 0, 0);       // read buf0, no stage, drain tile 127
  KSTEP(127, 1, 0, 0, 0);       // read buf1

  // ---- epilogue: D row=(lane>>4)*4+reg, col=lane&15 (m89-verified) ----
  const int r0 = tm0 + wr * 64 + ((lane >> 4) << 2);
  const int c0 = tn0 + wc * 64 + (lane & 15);
#pragma unroll
  for (int n = 0; n < 4; ++n) {
    float bv = bias[c0 + n * 16];
#pragma unroll
    for (int m = 0; m < 4; ++m) {
#pragma unroll
      for (int jj = 0; jj < 4; ++jj) {
        C[(size_t)(r0 + m * 16 + jj) * DOUT + c0 + n * 16] = acc[m][n][jj] + bv;
      }
    }
  }
#undef KSTEP
#undef STG
}

extern "C" void kernel_launch(void* const* d_in, const int* in_sizes, int n_in,
                              void* d_out, int out_size, void* d_ws, size_t ws_size,
                              hipStream_t stream) {
  const float* x    = (const float*)d_in[0];  // (4,2048,4096)
  const float* adv  = (const float*)d_in[1];  // (4096,128)
  const float* wfp  = (const float*)d_in[2];  // (4096,4096)
  const float* bias = (const float*)d_in[3];  // (4096,)
  const float* eps  = (const float*)d_in[4];  // (4096,128)

  float* out      = (float*)d_out;                    // 33554432
  float* eps_eff  = out + (size_t)MROWS * DOUT;       // 524288
  float* w_exps   = eps_eff + NG_W;                   // 524288
  float* act_exps = w_exps + NG_W;                    // 1048576

  bf16_t* xq = (bf16_t*)d_ws;                          // 67.1 MB
  bf16_t* wq = (bf16_t*)d_ws + (size_t)MROWS * DIN;    // +33.6 MB

  act_quant<<<NG_ACT / 256, 256, 0, stream>>>(x, xq, act_exps);
  w_quant<<<NG_W / 256, 256, 0, stream>>>(wfp, eps, adv, wq, eps_eff, w_exps);
  gemm_bt<<<dim3((MROWS / 128) * (DOUT / 128)), 256, 0, stream>>>(xq, wq, bias, out);
}

// Round 12
// 357.552 us; speedup vs baseline: 1.2006x; 1.2006x over previous
//
#include <hip/hip_runtime.h>
#include <hip/hip_bf16.h>

// Problem dims (fixed by setup_inputs): B=4, S=2048, DIN=4096, DOUT=4096, GS=32
#define DIN   4096
#define DOUT  4096
#define MROWS 8192            // B*S
#define GSIZE 32
#define NGPR  (DIN / GSIZE)   // groups per row = 128
#define NG_ACT (MROWS * NGPR) // 1048576
#define NG_W   (DOUT * NGPR)  // 524288

typedef __bf16 bf16_t;
typedef __attribute__((ext_vector_type(8))) __bf16 bf16x8;
typedef __attribute__((ext_vector_type(4))) float f32x4;

typedef const __attribute__((address_space(1))) void* gptr_t;
typedef __attribute__((address_space(3))) void* lptr_t;

// floor(log2(max(a,1))) grid rounding to the FP4 E2M1 set {0,±0.5,1,1.5,2,3,4,6}
__device__ __forceinline__ float fp4_round(float y) {
  float a  = __builtin_fabsf(y);
  float am = fmaxf(a, 1.0f);
  int   e  = (int)((__float_as_uint(am) >> 23) & 255u) - 127;  // floor(log2(max(a,1)))
  float step = __uint_as_float((unsigned)(e - 1 + 127) << 23); // 2^(e-1): 0.5, 1, 2
  float q = rintf(a / step) * step;  // RNE, matches jnp.round
  q = fminf(q, 6.0f);
  return copysignf(q, y);
}

// ---------------- activation quant: one thread per group of 32 ----------------
__global__ __launch_bounds__(256) void act_quant(const float* __restrict__ x,
                                                 bf16_t* __restrict__ xq,
                                                 float* __restrict__ exps_out) {
  int g = blockIdx.x * 256 + threadIdx.x;
  const float4* xp = reinterpret_cast<const float4*>(x) + (size_t)g * 8;
  float v[32];
  float amax = 0.f;
#pragma unroll
  for (int i = 0; i < 8; ++i) {
    float4 t = xp[i];
    v[4*i+0] = t.x; v[4*i+1] = t.y; v[4*i+2] = t.z; v[4*i+3] = t.w;
    amax = fmaxf(amax, fmaxf(fmaxf(__builtin_fabsf(t.x), __builtin_fabsf(t.y)),
                             fmaxf(__builtin_fabsf(t.z), __builtin_fabsf(t.w))));
  }
  float exps = 0.f;
  if (amax > 0.f) {
    float am = fmaxf(amax, 1e-30f);
    exps = (float)((int)((__float_as_uint(am) >> 23) & 255u) - 129);  // floor(log2)-2
  }
  float scale = __uint_as_float((unsigned)((int)exps + 127) << 23);   // 2^exps (exact)
  float inv   = __uint_as_float((unsigned)(127 - (int)exps) << 23);   // 2^-exps (exact)
  bf16x8 hv[4];
#pragma unroll
  for (int i = 0; i < 32; ++i) {
    float q = fp4_round(v[i] * inv) * scale;  // exact: pow2 scaling both ways
    hv[i >> 3][i & 7] = (bf16_t)q;            // exact in bf16 (<=2 mantissa bits * 2^e)
  }
  bf16x8* dst = reinterpret_cast<bf16x8*>(xq + (size_t)g * 32);
#pragma unroll
  for (int i = 0; i < 4; ++i) dst[i] = hv[i];
  exps_out[g] = exps;
}

// ---------------- weight quant with (1+eps_eff) scale ----------------
__global__ __launch_bounds__(256) void w_quant(const float* __restrict__ w,
                                               const float* __restrict__ eps,
                                               const float* __restrict__ adv,
                                               bf16_t* __restrict__ wq,
                                               float* __restrict__ eps_eff_out,
                                               float* __restrict__ w_exps_out) {
  int g = blockIdx.x * 256 + threadIdx.x;
  float ee = eps[g] + adv[g];
  eps_eff_out[g] = ee;
  const float4* wp = reinterpret_cast<const float4*>(w) + (size_t)g * 8;
  float v[32];
  float amax = 0.f;
#pragma unroll
  for (int i = 0; i < 8; ++i) {
    float4 t = wp[i];
    v[4*i+0] = t.x; v[4*i+1] = t.y; v[4*i+2] = t.z; v[4*i+3] = t.w;
    amax = fmaxf(amax, fmaxf(fmaxf(__builtin_fabsf(t.x), __builtin_fabsf(t.y)),
                             fmaxf(__builtin_fabsf(t.z), __builtin_fabsf(t.w))));
  }
  float exps = 0.f;
  if (amax > 0.f) {
    float am = fmaxf(amax, 1e-30f);
    exps = (float)((int)((__float_as_uint(am) >> 23) & 255u) - 129);
  }
  w_exps_out[g] = exps;
  float p2   = __uint_as_float((unsigned)((int)exps + 127) << 23);  // 2^exps
  float scale = p2 * (1.0f + ee);                                   // matches reference order
  bf16x8 hv[4];
#pragma unroll
  for (int i = 0; i < 32; ++i) {
    float q = fp4_round(v[i] / scale) * scale;  // IEEE div, matches reference
    hv[i >> 3][i & 7] = (bf16_t)q;              // only bf16-rounding error source
  }
  bf16x8* dst = reinterpret_cast<bf16x8*>(wq + (size_t)g * 32);
#pragma unroll
  for (int i = 0; i < 4; ++i) dst[i] = hv[i];
}

// ---------------- bf16 GEMM: C[M,N] = A[M,K] * B[N,K]^T + bias ----------------
// r12 = r11 pipeline with RACE-FREE staging. 256x256, BK=64, 8 waves (2Mx4N),
// 128 KiB LDS double-buffer. B of tile j register-held all iter (read at iter
// j-1 ph4); A read as 4 M-strips with 1-phase lag (alternating Ast0/Ast1).
// NO MFMA depends on same-phase reads -> derived lgkm waits are pre-serviced;
// LDS pipe runs concurrently with MFMA.
// r11's bug: A(j+2) staged in ph2/ph3 while those phases still read the same
// rows of tile j; L2-fast (~200cy) returns can land before the reads service.
// Fix: ALL 8 stage issues (A h0,h1 + B h0,h1 of tile j+2 -> buffer p) moved to
// ph4, after ph3's lgkm(0)+barrier pins every tile-j A-read serviced (B(j)'s
// buffer-p reads were serviced 4+ barriers earlier at iter j-1 ph4).
// Ledger: tile j+1's 8 loads issued iter j-1 ph4, drained at iter j ph3-end
// (vmcnt(0) with ~4 phases (~1200cy) cover -> ~free); ph4's 12 reads
// (B(j+1)+A(j+1)strip0 from p^1) then cross-wave safe.
// Per iter j (p=j&1):
//  ph1: rd A(j)strip1;                 barrier; MFMA strip0
//  ph2: rd A(j)strip2;                 barrier; MFMA strip1
//  ph3: rd A(j)strip3;                 barrier; MFMA strip2; lgkm(0); vmcnt(0)
//  ph4: rd B(j+1)x8 + A(j+1)strip0x4; stg tile j+2 (8 issues) -> p;
//       barrier; MFMA strip3
#define NT 64   // K-tiles

__global__ __launch_bounds__(512, 2) void gemm_bt(const bf16_t* __restrict__ A,
                                                  const bf16_t* __restrict__ B,
                                                  const float* __restrict__ bias,
                                                  float* __restrict__ C) {
  __shared__ bf16_t sA[2 * 16384];
  __shared__ bf16_t sB[2 * 16384];
  const int tid  = threadIdx.x;
  const int wave = tid >> 6;   // 0..7
  const int lane = tid & 63;

  // T1: bijective XCD swizzle (512 blocks, 512 % 8 == 0)
  const int swz = (blockIdx.x & 7) * 64 + (blockIdx.x >> 3);
  const int tm0 = (swz >> 4) * 256;   // 32 M-tiles
  const int tn0 = (swz & 15) * 256;   // 16 N-tiles

  const int wr = wave >> 2;   // 0..1 : M-half (128 rows)
  const int wc = wave & 3;    // 0..3 : N-quarter (64 cols)

  // ---- staging: each wave stages 16 rows of each 128-row half (2 gload_lds) ----
  const int lrow8 = lane >> 3;                    // 0..7
  const int csw   = ((lane & 7) ^ lrow8) * 8;     // T2 pre-swizzled src k-chunk
  const bf16_t* gA = A + (size_t)(tm0 + wave * 16 + lrow8) * DIN + csw;
  const bf16_t* gB = B + (size_t)(tn0 + wave * 16 + lrow8) * DIN + csw;
  const int stg0 = wave * 1024;  // elems

#define STGH(sM, gM, d, h, kt) do {                                          \
    const bf16_t* g_ = (gM) + (size_t)(h) * 128 * DIN + (size_t)(kt) * 64;   \
    __builtin_amdgcn_global_load_lds((gptr_t)g_,                             \
        (lptr_t)((sM) + (d) * 16384 + (h) * 8192 + stg0), 16, 0, 0);         \
    __builtin_amdgcn_global_load_lds((gptr_t)(g_ + 8 * DIN),                 \
        (lptr_t)((sM) + (d) * 16384 + (h) * 8192 + stg0 + 512), 16, 0, 0);   \
  } while (0)

  // ---- fragment read offsets (bytes): phys = row*128 + 16*((kk*4+(l>>4)) ^ (l&7))
  const int arow_b = (wr * 128 + (lane & 15)) * 128;
  const int brow_b = (wc * 64 + (lane & 15)) * 128;
  const int slot0  = (((lane >> 4) ^ (lane & 7)) << 4);   // kk=0; kk=1 -> ^0x40

  f32x4 acc[8][4] = {};
  bf16x8 Bs0[4][2], Bs1[4][2];   // B frag sets (parity)
  bf16x8 Ast0[2][2], Ast1[2][2]; // A strip sets (alternate by phase)

#define RDSTRIP(DST, BUFA, S) do {                                             \
    _Pragma("unroll")                                                          \
    for (int r_ = 0; r_ < 2; ++r_)                                             \
      _Pragma("unroll")                                                        \
      for (int kk_ = 0; kk_ < 2; ++kk_)                                        \
        DST[r_][kk_] = *reinterpret_cast<const bf16x8*>(                       \
            (BUFA) + arow_b + (2 * (S) + r_) * 2048 + (slot0 ^ (kk_ << 6)));   \
  } while (0)

#define RDB(DST, BUFB) do {                                                    \
    _Pragma("unroll")                                                          \
    for (int n_ = 0; n_ < 4; ++n_)                                             \
      _Pragma("unroll")                                                        \
      for (int kk_ = 0; kk_ < 2; ++kk_)                                        \
        DST[n_][kk_] = *reinterpret_cast<const bf16x8*>(                       \
            (BUFB) + brow_b + n_ * 2048 + (slot0 ^ (kk_ << 6)));               \
  } while (0)

#define MMAS(AST, BC, S) do {                                                  \
    __builtin_amdgcn_s_setprio(1);                                             \
    _Pragma("unroll")                                                          \
    for (int kk_ = 0; kk_ < 2; ++kk_)                                          \
      _Pragma("unroll")                                                        \
      for (int n_ = 0; n_ < 4; ++n_)                                           \
        _Pragma("unroll")                                                      \
        for (int r_ = 0; r_ < 2; ++r_)                                         \
          acc[2 * (S) + r_][n_] = __builtin_amdgcn_mfma_f32_16x16x32_bf16(     \
              AST[r_][kk_], BC[n_][kk_], acc[2 * (S) + r_][n_], 0, 0, 0);      \
    __builtin_amdgcn_s_setprio(0);                                             \
  } while (0)

#define ITER(J, BC, BN_) do {                                                  \
    const int p_ = (J) & 1;                                                    \
    const char* bA_  = (const char*)sA + p_ * 32768;                           \
    const char* bA2_ = (const char*)sA + (p_ ^ 1) * 32768;                     \
    const char* bB2_ = (const char*)sB + (p_ ^ 1) * 32768;                     \
    /* -- ph1: rd strip1; MFMA strip0 -- */                                    \
    RDSTRIP(Ast1, bA_, 1);                                                     \
    __builtin_amdgcn_s_barrier();                                              \
    MMAS(Ast0, BC, 0);                                                         \
    __builtin_amdgcn_s_barrier();                                              \
    /* -- ph2: rd strip2; MFMA strip1 -- */                                    \
    RDSTRIP(Ast0, bA_, 2);                                                     \
    __builtin_amdgcn_s_barrier();                                              \
    MMAS(Ast1, BC, 1);                                                         \
    __builtin_amdgcn_s_barrier();                                              \
    /* -- ph3: rd strip3; MFMA strip2; pin reads; drain tile J+1 -- */         \
    RDSTRIP(Ast1, bA_, 3);                                                     \
    __builtin_amdgcn_s_barrier();                                              \
    MMAS(Ast0, BC, 2);                                                         \
    asm volatile("s_waitcnt lgkmcnt(0)");   /* all tile-J A reads serviced */  \
    asm volatile("s_waitcnt vmcnt(0)");     /* tile J+1 landed (4-ph cover) */ \
    __builtin_amdgcn_s_barrier();                                              \
    /* -- ph4: rd B(J+1)+A(J+1)strip0; stg tile J+2 -> p; MFMA strip3 -- */    \
    if ((J) + 1 < NT) { RDB(BN_, bB2_); RDSTRIP(Ast0, bA2_, 0); }              \
    if ((J) + 2 < NT) { STGH(sA, gA, p_, 0, (J) + 2);                          \
                        STGH(sA, gA, p_, 1, (J) + 2);                          \
                        STGH(sB, gB, p_, 0, (J) + 2);                          \
                        STGH(sB, gB, p_, 1, (J) + 2); }                        \
    __builtin_amdgcn_s_barrier();                                              \
    MMAS(Ast1, BC, 3);                                                         \
    __builtin_amdgcn_s_barrier();                                              \
  } while (0)

  // ---- prologue: stage tiles 0,1; tile 0 landed; read B(0)+A(0)strip0 ----
  STGH(sA, gA, 0, 0, 0); STGH(sA, gA, 0, 1, 0);
  STGH(sB, gB, 0, 0, 0); STGH(sB, gB, 0, 1, 0);
  STGH(sA, gA, 1, 0, 1); STGH(sA, gA, 1, 1, 1);
  STGH(sB, gB, 1, 0, 1); STGH(sB, gB, 1, 1, 1);
  asm volatile("s_waitcnt vmcnt(8)");       // tile 0 landed; tile 1 in flight
  __builtin_amdgcn_s_barrier();
  RDB(Bs0, (const char*)sB);
  RDSTRIP(Ast0, (const char*)sA, 0);

  for (int j = 0; j < NT; j += 2) {
    ITER(j, Bs0, Bs1);
    ITER(j + 1, Bs1, Bs0);
  }

  // ---- epilogue: D row=(lane>>4)*4+reg, col=lane&15 (m89-verified) ----
  const int r0 = tm0 + wr * 128 + ((lane >> 4) << 2);
  const int c0 = tn0 + wc * 64 + (lane & 15);
#pragma unroll
  for (int n = 0; n < 4; ++n) {
    float bv = bias[c0 + n * 16];
#pragma unroll
    for (int m = 0; m < 8; ++m) {
#pragma unroll
      for (int jj = 0; jj < 4; ++jj) {
        C[(size_t)(r0 + m * 16 + jj) * DOUT + c0 + n * 16] = acc[m][n][jj] + bv;
      }
    }
  }
#undef ITER
#undef MMAS
#undef RDB
#undef RDSTRIP
#undef STGH
}

extern "C" void kernel_launch(void* const* d_in, const int* in_sizes, int n_in,
                              void* d_out, int out_size, void* d_ws, size_t ws_size,
                              hipStream_t stream) {
  const float* x    = (const float*)d_in[0];  // (4,2048,4096)
  const float* adv  = (const float*)d_in[1];  // (4096,128)
  const float* wfp  = (const float*)d_in[2];  // (4096,4096)
  const float* bias = (const float*)d_in[3];  // (4096,)
  const float* eps  = (const float*)d_in[4];  // (4096,128)

  float* out      = (float*)d_out;                    // 33554432
  float* eps_eff  = out + (size_t)MROWS * DOUT;       // 524288
  float* w_exps   = eps_eff + NG_W;                   // 524288
  float* act_exps = w_exps + NG_W;                    // 1048576

  bf16_t* xq = (bf16_t*)d_ws;                          // 67.1 MB
  bf16_t* wq = (bf16_t*)d_ws + (size_t)MROWS * DIN;    // +33.6 MB

  act_quant<<<NG_ACT / 256, 256, 0, stream>>>(x, xq, act_exps);
  w_quant<<<NG_W / 256, 256, 0, stream>>>(wfp, eps, adv, wq, eps_eff, w_exps);
  gemm_bt<<<dim3((MROWS / 256) * (DOUT / 256)), 512, 0, stream>>>(xq, wq, bias, out);
}

// Round 13
// 333.552 us; speedup vs baseline: 1.2870x; 1.0720x over previous
//
#include <hip/hip_runtime.h>
#include <hip/hip_bf16.h>

// Problem dims (fixed by setup_inputs): B=4, S=2048, DIN=4096, DOUT=4096, GS=32
#define DIN   4096
#define DOUT  4096
#define MROWS 8192            // B*S
#define GSIZE 32
#define NGPR  (DIN / GSIZE)   // groups per row = 128
#define NG_ACT (MROWS * NGPR) // 1048576
#define NG_W   (DOUT * NGPR)  // 524288

typedef __bf16 bf16_t;
typedef __attribute__((ext_vector_type(8))) __bf16 bf16x8;
typedef __attribute__((ext_vector_type(4))) float f32x4;

typedef const __attribute__((address_space(1))) void* gptr_t;
typedef __attribute__((address_space(3))) void* lptr_t;

// floor(log2(max(a,1))) grid rounding to the FP4 E2M1 set {0,±0.5,1,1.5,2,3,4,6}
__device__ __forceinline__ float fp4_round(float y) {
  float a  = __builtin_fabsf(y);
  float am = fmaxf(a, 1.0f);
  int   e  = (int)((__float_as_uint(am) >> 23) & 255u) - 127;  // floor(log2(max(a,1)))
  float step = __uint_as_float((unsigned)(e - 1 + 127) << 23); // 2^(e-1): 0.5, 1, 2
  float q = rintf(a / step) * step;  // RNE, matches jnp.round
  q = fminf(q, 6.0f);
  return copysignf(q, y);
}

// ---------------- fused quant: one thread per group of 32 ----------------
// Blocks [0, NG_ACT/256): activation groups (pow2 scale, exact path).
// Blocks [NG_ACT/256, ...): weight groups with (1+eps_eff) scale.
__global__ __launch_bounds__(256) void fused_quant(const float* __restrict__ x,
                                                   const float* __restrict__ w,
                                                   const float* __restrict__ eps,
                                                   const float* __restrict__ adv,
                                                   bf16_t* __restrict__ xq,
                                                   bf16_t* __restrict__ wq,
                                                   float* __restrict__ act_exps,
                                                   float* __restrict__ eps_eff_out,
                                                   float* __restrict__ w_exps_out) {
  const int bid = blockIdx.x;
  const bool is_w = bid >= (NG_ACT / 256);
  const int g = (is_w ? (bid - NG_ACT / 256) : bid) * 256 + threadIdx.x;

  const float* src = is_w ? w : x;
  const float4* sp = reinterpret_cast<const float4*>(src) + (size_t)g * 8;
  float v[32];
  float amax = 0.f;
#pragma unroll
  for (int i = 0; i < 8; ++i) {
    float4 t = sp[i];
    v[4*i+0] = t.x; v[4*i+1] = t.y; v[4*i+2] = t.z; v[4*i+3] = t.w;
    amax = fmaxf(amax, fmaxf(fmaxf(__builtin_fabsf(t.x), __builtin_fabsf(t.y)),
                             fmaxf(__builtin_fabsf(t.z), __builtin_fabsf(t.w))));
  }
  float exps = 0.f;
  if (amax > 0.f) {
    float am = fmaxf(amax, 1e-30f);
    exps = (float)((int)((__float_as_uint(am) >> 23) & 255u) - 129);  // floor(log2)-2
  }
  bf16x8 hv[4];
  if (!is_w) {
    // exact pow2 scaling both ways; bf16 write exact (<=2 mantissa bits * 2^e)
    float scale = __uint_as_float((unsigned)((int)exps + 127) << 23);   // 2^exps
    float inv   = __uint_as_float((unsigned)(127 - (int)exps) << 23);   // 2^-exps
#pragma unroll
    for (int i = 0; i < 32; ++i) {
      float q = fp4_round(v[i] * inv) * scale;
      hv[i >> 3][i & 7] = (bf16_t)q;
    }
    bf16x8* dst = reinterpret_cast<bf16x8*>(xq + (size_t)g * 32);
#pragma unroll
    for (int i = 0; i < 4; ++i) dst[i] = hv[i];
    act_exps[g] = exps;
  } else {
    float ee = eps[g] + adv[g];
    eps_eff_out[g] = ee;
    w_exps_out[g] = exps;
    float p2    = __uint_as_float((unsigned)((int)exps + 127) << 23);  // 2^exps
    float scale = p2 * (1.0f + ee);            // matches reference order
#pragma unroll
    for (int i = 0; i < 32; ++i) {
      float q = fp4_round(v[i] / scale) * scale;  // IEEE div, matches reference
      hv[i >> 3][i & 7] = (bf16_t)q;              // only bf16-rounding error source
    }
    bf16x8* dst = reinterpret_cast<bf16x8*>(wq + (size_t)g * 32);
#pragma unroll
    for (int i = 0; i < 4; ++i) dst[i] = hv[i];
  }
}

// ---------------- bf16 GEMM: C[M,N] = A[M,K] * B[N,K]^T + bias ----------------
// r13 = r7 (best verified: 306us GEMM, 898 TF, MfmaUtil 38%, 0 bank conflicts).
// 256x256 tile, BK=64, 8 waves (2Mx4N), 512 thr, 128 KiB LDS double-buffer.
// Derived waits (no explicit lgkmcnt), builtin barriers, deep staging:
//   ph1: ds a-lo(8)+b-lo(4); Q0   ph2: ds b-hi(4); Q1 (B(p) free)
//   ph3: ds a-hi(8); stage B(j+2); Q2 (A(p) free)   ph4: stage A(j+2); Q3
//   vmcnt(8) once per K-tile (tile j+1 retired, issued 4-6 phases earlier;
//   tile j+2's 8 loads stay in flight). Never vmcnt(0) in steady state.
// Empirical note: 8 structural variants (r4-r12: lagged reads, reg-pipelined
// operands, explicit waits, 128^2 TLP) all land 900-930 TF; this schedule
// family's plateau on MI355X.
#define NT 64   // K-tiles

__global__ __launch_bounds__(512, 2) void gemm_bt(const bf16_t* __restrict__ A,
                                                  const bf16_t* __restrict__ B,
                                                  const float* __restrict__ bias,
                                                  float* __restrict__ C) {
  __shared__ bf16_t sA[2 * 16384];
  __shared__ bf16_t sB[2 * 16384];
  const int tid  = threadIdx.x;
  const int wave = tid >> 6;   // 0..7
  const int lane = tid & 63;

  // T1: bijective XCD swizzle (512 blocks, 512 % 8 == 0)
  const int swz = (blockIdx.x & 7) * 64 + (blockIdx.x >> 3);
  const int tm0 = (swz >> 4) * 256;   // 32 M-tiles
  const int tn0 = (swz & 15) * 256;   // 16 N-tiles

  const int wr = wave >> 2;   // 0..1 : M-half (128 rows)
  const int wc = wave & 3;    // 0..3 : N-quarter (64 cols)

  // ---- half-tile staging: each wave stages 16 rows of each 128-row half ----
  const int lrow8 = lane >> 3;                    // 0..7
  const int csw   = ((lane & 7) ^ lrow8) * 8;     // T2 pre-swizzled src k-chunk
  const bf16_t* gA = A + (size_t)(tm0 + wave * 16 + lrow8) * DIN + csw;
  const bf16_t* gB = B + (size_t)(tn0 + wave * 16 + lrow8) * DIN + csw;
  const int stg0 = wave * 1024;  // elems

#define STGH(sM, gM, d, h, kt) do {                                          \
    const bf16_t* g_ = (gM) + (size_t)(h) * 128 * DIN + (size_t)(kt) * 64;   \
    __builtin_amdgcn_global_load_lds((gptr_t)g_,                             \
        (lptr_t)((sM) + (d) * 16384 + (h) * 8192 + stg0), 16, 0, 0);         \
    __builtin_amdgcn_global_load_lds((gptr_t)(g_ + 8 * DIN),                 \
        (lptr_t)((sM) + (d) * 16384 + (h) * 8192 + stg0 + 512), 16, 0, 0);   \
  } while (0)

  // ---- fragment read offsets (bytes): phys = row*128 + 16*((kk*4+(l>>4)) ^ (l&7))
  const int arow_b = (wr * 128 + (lane & 15)) * 128;
  const int brow_b = (wc * 64 + (lane & 15)) * 128;
  const int slot0  = (((lane >> 4) ^ (lane & 7)) << 4);   // kk=0; kk=1 -> ^0x40

  f32x4 acc[8][4] = {};

  // ---- prologue: stage K-tiles 0 and 1 fully; wait for tile 0 ----
  STGH(sA, gA, 0, 0, 0); STGH(sA, gA, 0, 1, 0);
  STGH(sB, gB, 0, 0, 0); STGH(sB, gB, 0, 1, 0);
  STGH(sB, gB, 1, 0, 1); STGH(sB, gB, 1, 1, 1);
  STGH(sA, gA, 1, 0, 1); STGH(sA, gA, 1, 1, 1);
  asm volatile("s_waitcnt vmcnt(8)");       // tile 0's 8 loads retired
  __builtin_amdgcn_s_barrier();

  for (int j = 0; j < NT; ++j) {
    const int p = j & 1;
    const char* bufA = (const char*)sA + p * 32768;
    const char* bufB = (const char*)sB + p * 32768;
    bf16x8 a0[4][2], a1[4][2], bn[4][2];

    // ======== phase 1: ds a-lo(8)+b-lo(4); Q0 = mlo x nlo ========
#pragma unroll
    for (int m = 0; m < 4; ++m)
#pragma unroll
      for (int kk = 0; kk < 2; ++kk)
        a0[m][kk] = *reinterpret_cast<const bf16x8*>(bufA + arow_b + m * 2048 + (slot0 ^ (kk << 6)));
#pragma unroll
    for (int t = 0; t < 2; ++t)
#pragma unroll
      for (int kk = 0; kk < 2; ++kk)
        bn[t][kk] = *reinterpret_cast<const bf16x8*>(bufB + brow_b + t * 2048 + (slot0 ^ (kk << 6)));
    __builtin_amdgcn_s_barrier();
    __builtin_amdgcn_s_setprio(1);
#pragma unroll
    for (int kk = 0; kk < 2; ++kk)
#pragma unroll
      for (int t = 0; t < 2; ++t)
#pragma unroll
        for (int m = 0; m < 4; ++m)
          acc[m][t] = __builtin_amdgcn_mfma_f32_16x16x32_bf16(a0[m][kk], bn[t][kk], acc[m][t], 0, 0, 0);
    __builtin_amdgcn_s_setprio(0);
    __builtin_amdgcn_s_barrier();

    // ======== phase 2: ds b-hi(4); Q1 = mlo x nhi (reuses a0) ========
#pragma unroll
    for (int t = 2; t < 4; ++t)
#pragma unroll
      for (int kk = 0; kk < 2; ++kk)
        bn[t][kk] = *reinterpret_cast<const bf16x8*>(bufB + brow_b + t * 2048 + (slot0 ^ (kk << 6)));
    __builtin_amdgcn_s_barrier();
    __builtin_amdgcn_s_setprio(1);
#pragma unroll
    for (int kk = 0; kk < 2; ++kk)
#pragma unroll
      for (int t = 0; t < 2; ++t)
#pragma unroll
        for (int m = 0; m < 4; ++m)
          acc[m][2 + t] = __builtin_amdgcn_mfma_f32_16x16x32_bf16(a0[m][kk], bn[2 + t][kk], acc[m][2 + t], 0, 0, 0);
    __builtin_amdgcn_s_setprio(0);
    __builtin_amdgcn_s_barrier();

    // ======== phase 3: ds a-hi(8); stage B(j+2)->p; Q2 = mhi x nlo ========
#pragma unroll
    for (int m = 0; m < 4; ++m)
#pragma unroll
      for (int kk = 0; kk < 2; ++kk)
        a1[m][kk] = *reinterpret_cast<const bf16x8*>(bufA + arow_b + (4 + m) * 2048 + (slot0 ^ (kk << 6)));
    if (j + 2 < NT) {
      STGH(sB, gB, p, 0, j + 2);
      STGH(sB, gB, p, 1, j + 2);
    }
    __builtin_amdgcn_s_barrier();
    __builtin_amdgcn_s_setprio(1);
#pragma unroll
    for (int kk = 0; kk < 2; ++kk)
#pragma unroll
      for (int t = 0; t < 2; ++t)
#pragma unroll
        for (int m = 0; m < 4; ++m)
          acc[4 + m][t] = __builtin_amdgcn_mfma_f32_16x16x32_bf16(a1[m][kk], bn[t][kk], acc[4 + m][t], 0, 0, 0);
    __builtin_amdgcn_s_setprio(0);
    __builtin_amdgcn_s_barrier();

    // ======== phase 4: stage A(j+2)->p; Q3 = mhi x nhi; counted vmcnt ========
    if (j + 2 < NT) {
      STGH(sA, gA, p, 0, j + 2);
      STGH(sA, gA, p, 1, j + 2);
    }
    __builtin_amdgcn_s_barrier();
    __builtin_amdgcn_s_setprio(1);
#pragma unroll
    for (int kk = 0; kk < 2; ++kk)
#pragma unroll
      for (int t = 0; t < 2; ++t)
#pragma unroll
        for (int m = 0; m < 4; ++m)
          acc[4 + m][2 + t] = __builtin_amdgcn_mfma_f32_16x16x32_bf16(a1[m][kk], bn[2 + t][kk], acc[4 + m][2 + t], 0, 0, 0);
    __builtin_amdgcn_s_setprio(0);
    if (j < NT - 2) {
      asm volatile("s_waitcnt vmcnt(8)");   // tile j+1 landed; tile j+2 in flight
    } else {
      asm volatile("s_waitcnt vmcnt(0)");   // tail drain
    }
    __builtin_amdgcn_s_barrier();
  }

  // ---- epilogue: D row=(lane>>4)*4+reg, col=lane&15 (m89-verified) ----
  const int r0 = tm0 + wr * 128 + ((lane >> 4) << 2);
  const int c0 = tn0 + wc * 64 + (lane & 15);
#pragma unroll
  for (int n = 0; n < 4; ++n) {
    float bv = bias[c0 + n * 16];
#pragma unroll
    for (int m = 0; m < 8; ++m) {
#pragma unroll
      for (int jj = 0; jj < 4; ++jj) {
        C[(size_t)(r0 + m * 16 + jj) * DOUT + c0 + n * 16] = acc[m][n][jj] + bv;
      }
    }
  }
#undef STGH
}

extern "C" void kernel_launch(void* const* d_in, const int* in_sizes, int n_in,
                              void* d_out, int out_size, void* d_ws, size_t ws_size,
                              hipStream_t stream) {
  const float* x    = (const float*)d_in[0];  // (4,2048,4096)
  const float* adv  = (const float*)d_in[1];  // (4096,128)
  const float* wfp  = (const float*)d_in[2];  // (4096,4096)
  const float* bias = (const float*)d_in[3];  // (4096,)
  const float* eps  = (const float*)d_in[4];  // (4096,128)

  float* out      = (float*)d_out;                    // 33554432
  float* eps_eff  = out + (size_t)MROWS * DOUT;       // 524288
  float* w_exps   = eps_eff + NG_W;                   // 524288
  float* act_exps = w_exps + NG_W;                    // 1048576

  bf16_t* xq = (bf16_t*)d_ws;                          // 67.1 MB
  bf16_t* wq = (bf16_t*)d_ws + (size_t)MROWS * DIN;    // +33.6 MB

  fused_quant<<<(NG_ACT + NG_W) / 256, 256, 0, stream>>>(
      x, wfp, eps, adv, xq, wq, act_exps, eps_eff, w_exps);
  gemm_bt<<<dim3((MROWS / 256) * (DOUT / 256)), 512, 0, stream>>>(xq, wq, bias, out);
}